// Round 10
// baseline (613.485 us; speedup 1.0000x reference)
//
#include <hip/hip_runtime.h>

#define NN 10000
#define NE 640000

typedef __attribute__((ext_vector_type(8))) short bf16x8;
typedef __attribute__((ext_vector_type(4))) short s16x4;
typedef __attribute__((ext_vector_type(4))) float f32x4;

#define MFMA __builtin_amdgcn_mfma_f32_16x16x32_bf16

static __device__ __forceinline__ float silu_f(float x) {
    return x / (1.f + __expf(-x));
}
// fast silu: v_rcp_f32 (1 ulp) — output is bf16-rounded anyway
static __device__ __forceinline__ float silu_fast(float x) {
    float d = 1.f + __expf(-x);
    float r; asm("v_rcp_f32 %0, %1" : "=v"(r) : "v"(d));
    return x * r;
}
static __device__ __forceinline__ short f2bf(float x) {   // RNE f32->bf16
    union { float f; unsigned u; } v; v.f = x;
    unsigned r = (v.u + 0x7FFF + ((v.u >> 16) & 1)) >> 16;
    return (short)r;
}
static __device__ __forceinline__ float bf2f(short h) {
    union { float f; unsigned u; } v; v.u = ((unsigned)(unsigned short)h) << 16;
    return v.f;
}

// ---------------- CSR build ---------------------------------------------------
__global__ __launch_bounds__(256) void k_hist(const int* __restrict__ dst,
                                              int* __restrict__ cnt) {
    int e = blockIdx.x * 256 + threadIdx.x;
    if (e < NE) atomicAdd(&cnt[dst[e]], 1);
}

__global__ __launch_bounds__(256) void k_scan(const int* __restrict__ cnt,
                                              int* __restrict__ row_start,
                                              int* __restrict__ cursor) {
    __shared__ int sv[NN];
    __shared__ int part[256];
    __shared__ int base[257];
    const int t = threadIdx.x;
    for (int i = t; i < NN; i += 256) sv[i] = cnt[i];
    __syncthreads();
    int s = 0;
    #pragma unroll
    for (int i = 0; i < 40; i++) {
        int idx = t * 40 + i;
        int v = (idx < NN) ? sv[idx] : 0;
        if (idx < NN) sv[idx] = s;
        s += v;
    }
    part[t] = s;
    __syncthreads();
    if (t == 0) {
        int a = 0;
        for (int j = 0; j < 256; j++) { base[j] = a; a += part[j]; }
        base[256] = a;
    }
    __syncthreads();
    for (int i = t; i < NN; i += 256) {
        int v = base[i / 40] + sv[i];
        row_start[i] = v; cursor[i] = v;
    }
    if (t == 0) row_start[NN] = base[256];
}

__global__ __launch_bounds__(256) void k_scatter(const int* __restrict__ dst,
                                                 int* __restrict__ cursor,
                                                 int* __restrict__ perm) {
    int e = blockIdx.x * 256 + threadIdx.x;
    if (e < NE) {
        int d = dst[e];
        int p = atomicAdd(&cursor[d], 1);
        perm[p] = e;
    }
}

__global__ __launch_bounds__(256) void k_pack(
    const int* __restrict__ perm, const int* __restrict__ src,
    const int* __restrict__ dst, const float* __restrict__ ef,
    const float* __restrict__ coord,
    int* __restrict__ src_s, unsigned short* __restrict__ dist_s,
    unsigned short* __restrict__ efs)
{
    int p = blockIdx.x * 256 + threadIdx.x;
    if (p >= NE) return;
    const int e = perm[p];
    const int s = src[e];
    const int d = dst[e];

    const float dx = coord[s*3+0] - coord[d*3+0];
    const float dy = coord[s*3+1] - coord[d*3+1];
    const float dz = coord[s*3+2] - coord[d*3+2];
    const float dist = sqrtf(dx*dx + dy*dy + dz*dz);

    src_s[p] = s;
    dist_s[p] = (unsigned short)f2bf(dist);

    const float4* ep = (const float4*)(ef + (size_t)e*16);
    #pragma unroll
    for (int j = 0; j < 4; j++) {
        float4 a = ep[j];
        s16x4 p4;
        p4[0] = f2bf(a.x); p4[1] = f2bf(a.y); p4[2] = f2bf(a.z); p4[3] = f2bf(a.w);
        *(s16x4*)&efs[(size_t)p*16 + j*4] = p4;
    }
}

// ---------------- node precompute --------------------------------------------
__global__ __launch_bounds__(256) void node_pre_kernel(
    const float* __restrict__ node_feat,
    const float* __restrict__ W_e1,   // [145][64]
    const float* __restrict__ W_k,    // [81][64]
    const float* __restrict__ W_q,    // [64][64]
    short* __restrict__ nfb, float* __restrict__ B,
    float* __restrict__ G, float* __restrict__ EQn, float* __restrict__ WQn)
{
    __shared__ float sW1b[64*64];
    __shared__ float sWq[64*64];
    __shared__ float sWk[64*65];
    __shared__ float sWke[16*65];
    __shared__ __align__(16) float sx[4][64];
    __shared__ __align__(16) float sq[4][64];

    for (int i = threadIdx.x; i < 64*64; i += 256) {
        sW1b[i] = W_e1[64*64 + i];
        sWq[i]  = W_q[i];
        int c = i >> 6, j = i & 63;
        sWk[c*65 + j] = W_k[i];
    }
    for (int i = threadIdx.x; i < 16*64; i += 256) {
        int k = i >> 6, j = i & 63;
        sWke[k*65 + j] = W_k[(65 + k)*64 + j];
    }
    __syncthreads();

    const int wid = threadIdx.x >> 6;
    const int lane = threadIdx.x & 63;
    for (int n = blockIdx.x * 4 + wid; n < NN; n += gridDim.x * 4) {
        float x = node_feat[n*64 + lane];
        nfb[n*64 + lane] = f2bf(x);
        sx[wid][lane] = x;
        float b = 0.f, q = 0.f;
        #pragma unroll
        for (int i = 0; i < 64; i += 4) {
            float4 x4 = *(const float4*)&sx[wid][i];
            b += x4.x*sW1b[(i+0)*64+lane] + x4.y*sW1b[(i+1)*64+lane]
               + x4.z*sW1b[(i+2)*64+lane] + x4.w*sW1b[(i+3)*64+lane];
            q += x4.x*sWq[(i+0)*64+lane] + x4.y*sWq[(i+1)*64+lane]
               + x4.z*sWq[(i+2)*64+lane] + x4.w*sWq[(i+3)*64+lane];
        }
        B[n*64 + lane] = b;
        sq[wid][lane] = q;

        float g = 0.f;
        #pragma unroll
        for (int j = 0; j < 64; j += 4) {
            float4 q4 = *(const float4*)&sq[wid][j];
            g += q4.x*sWk[lane*65 + j]   + q4.y*sWk[lane*65 + j+1]
               + q4.z*sWk[lane*65 + j+2] + q4.w*sWk[lane*65 + j+3];
        }
        G[n*64 + lane] = g;

        float p = W_k[64*64 + lane] * q;
        #pragma unroll
        for (int off = 32; off; off >>= 1) p += __shfl_xor(p, off);
        if (lane == 0) WQn[n] = p;

        int kk = lane & 15, pp = lane >> 4;
        float s = 0.f;
        #pragma unroll
        for (int jj = 0; jj < 16; jj++) {
            int j = pp*16 + jj;
            s += sWke[kk*65 + j] * sq[wid][j];
        }
        s += __shfl_xor(s, 16); s += __shfl_xor(s, 32);
        if (lane < 16) EQn[n*16 + kk] = s;
    }
}

// ---------------- edge pass: wave/node, software-pipelined, no sX ------------
// A operands loaded DIRECTLY in MFMA layout: lane(cl,rg) holds edge c0+cl,
// k-chunk rg*8. Score = uniform dot vs sC=[G|EQn|wq|0..] (dist rides k=80).
// Pipeline: M2 of tile t-1 (from sH1) overlaps M1 of tile t; one drain iter.
__global__ __launch_bounds__(512, 4) void edge_kernel(
    const short* __restrict__ nfb, const int* __restrict__ src_s,
    const unsigned short* __restrict__ dist_s,
    const unsigned short* __restrict__ efs, const int* __restrict__ row_start,
    const float* __restrict__ W_e1, const float* __restrict__ b_e1,
    const float* __restrict__ W_e2, const float* __restrict__ b_e2,
    const float* __restrict__ B, const float* __restrict__ G,
    const float* __restrict__ EQn, const float* __restrict__ WQn,
    float* __restrict__ hout)
{
    __shared__ short sW1T[64*104];     // [phys slot][k], k<96 used, pads zero
    __shared__ short sW2T[64*72];      // [phys slot][k]
    __shared__ short sH1[8][16*72];    // per-wave [edge][logical c]
    __shared__ __align__(16) float sC[8][96];   // per-wave score coeffs

    const int tid = threadIdx.x;
    const int wid = tid >> 6, l = tid & 63;
    const int cl = l & 15, rg = l >> 4;

    for (int i = tid; i < 64*104; i += 512) sW1T[i] = 0;
    __syncthreads();
    for (int i = tid; i < 64*82; i += 512) {
        int k = i >> 6, c = i & 63;              // c = LOGICAL output col
        float v;
        if (k < 64)       v = W_e1[k*64 + c];
        else if (k < 80)  v = W_e1[(129 + k - 64)*64 + c];
        else if (k == 80) v = W_e1[128*64 + c];
        else              v = b_e1[c];
        int s = (c & 3) * 16 + (c >> 2);          // physical MFMA col slot
        sW1T[s*104 + k] = f2bf(v);
    }
    for (int i = tid; i < 64*64; i += 512) {
        int k = i >> 6, c = i & 63;
        int s = (c & 3) * 16 + (c >> 2);
        sW2T[s*72 + k] = f2bf(W_e2[k*64 + c]);
    }
    __syncthreads();

    const float4 b24 = *(const float4*)&b_e2[cl*4];   // same for all nodes

    for (int n = blockIdx.x * 8 + wid; n < NN; n += gridDim.x * 8) {
        const int beg = row_start[n], end = row_start[n+1];
        const size_t nb = (size_t)n*64;
        const float4 Bb4 = *(const float4*)&B[nb + cl*4];

        // score coefficient vector: [0..63]=G, [64..79]=EQn, [80]=wq, [81..95]=0
        sC[wid][l] = G[nb + l];
        if (l < 16) sC[wid][64 + l] = EQn[(size_t)n*16 + l];
        if (l == 16) sC[wid][80] = WQn[n];
        if (l >= 17 && l < 32) sC[wid][64 + l] = 0.f;

        // zero this wave's sH1 (pipeline stage -1)
        {
            unsigned* hp = (unsigned*)&sH1[wid][0];
            #pragma unroll
            for (int i = l; i < 576; i += 64) hp[i] = 0u;
        }

        float hs0 = 0.f, hs1 = 0.f, hs2 = 0.f, hs3 = 0.f, den = 0.f;
        float w_prev = 0.f;

        // ---- prefetch tile 0 (direct, consumer layout) ----
        bf16x8 pA, pB, pE;
        #pragma unroll
        for (int i = 0; i < 8; i++) pE[i] = 0;
        unsigned short pD = 0;
        {
            int idx = beg + cl; if (idx > NE-1) idx = NE-1;
            int sN = src_s[idx];
            pA = *(const bf16x8*)&nfb[(size_t)sN*64 + rg*8];
            pB = *(const bf16x8*)&nfb[(size_t)sN*64 + 32 + rg*8];
            if (rg < 2)       pE = *(const bf16x8*)&efs[(size_t)idx*16 + rg*8];
            else if (rg == 2) pD = dist_s[idx];
        }

        for (int c0 = beg; c0 < end + 16; c0 += 16) {
            // ---- read previous tile's H1 (zeros on first iter) ----
            bf16x8 ah0 = *(const bf16x8*)&sH1[wid][cl*72 + rg*8];
            bf16x8 ah1 = *(const bf16x8*)&sH1[wid][cl*72 + 32 + rg*8];

            // rotate prefetch -> current
            bf16x8 ax0 = pA, ax1 = pB, pEc = pE;
            unsigned short pDc = pD;

            // issue next-tile prefetch
            {
                int idx2 = c0 + 16 + cl; if (idx2 > NE-1) idx2 = NE-1;
                int sN = src_s[idx2];
                pA = *(const bf16x8*)&nfb[(size_t)sN*64 + rg*8];
                pB = *(const bf16x8*)&nfb[(size_t)sN*64 + 32 + rg*8];
                if (rg < 2)       pE = *(const bf16x8*)&efs[(size_t)idx2*16 + rg*8];
                else if (rg == 2) pD = dist_s[idx2];
            }

            // build ax2: rg0/1 = ef chunks, rg2 = {dist, 1, 0..}, rg3 = 0
            bf16x8 ax2;
            #pragma unroll
            for (int i = 0; i < 8; i++) ax2[i] = 0;
            if (rg < 2) ax2 = pEc;
            else if (rg == 2) { ax2[0] = (short)pDc; ax2[1] = (short)0x3F80; }

            // ---- M1 (tile t): K=96, C-init = B[dst] ----
            f32x4 a0 = {Bb4.x,Bb4.x,Bb4.x,Bb4.x}, a1 = {Bb4.y,Bb4.y,Bb4.y,Bb4.y};
            f32x4 a2 = {Bb4.z,Bb4.z,Bb4.z,Bb4.z}, a3 = {Bb4.w,Bb4.w,Bb4.w,Bb4.w};
            a0 = MFMA(ax0, *(const bf16x8*)&sW1T[( 0+cl)*104 +  0 + rg*8], a0, 0,0,0);
            a0 = MFMA(ax1, *(const bf16x8*)&sW1T[( 0+cl)*104 + 32 + rg*8], a0, 0,0,0);
            a0 = MFMA(ax2, *(const bf16x8*)&sW1T[( 0+cl)*104 + 64 + rg*8], a0, 0,0,0);
            a1 = MFMA(ax0, *(const bf16x8*)&sW1T[(16+cl)*104 +  0 + rg*8], a1, 0,0,0);
            a1 = MFMA(ax1, *(const bf16x8*)&sW1T[(16+cl)*104 + 32 + rg*8], a1, 0,0,0);
            a1 = MFMA(ax2, *(const bf16x8*)&sW1T[(16+cl)*104 + 64 + rg*8], a1, 0,0,0);
            a2 = MFMA(ax0, *(const bf16x8*)&sW1T[(32+cl)*104 +  0 + rg*8], a2, 0,0,0);
            a2 = MFMA(ax1, *(const bf16x8*)&sW1T[(32+cl)*104 + 32 + rg*8], a2, 0,0,0);
            a2 = MFMA(ax2, *(const bf16x8*)&sW1T[(32+cl)*104 + 64 + rg*8], a2, 0,0,0);
            a3 = MFMA(ax0, *(const bf16x8*)&sW1T[(48+cl)*104 +  0 + rg*8], a3, 0,0,0);
            a3 = MFMA(ax1, *(const bf16x8*)&sW1T[(48+cl)*104 + 32 + rg*8], a3, 0,0,0);
            a3 = MFMA(ax2, *(const bf16x8*)&sW1T[(48+cl)*104 + 64 + rg*8], a3, 0,0,0);

            // ---- M2 (tile t-1), independent of M1 ----
            f32x4 c0v = {b24.x,b24.x,b24.x,b24.x}, c1v = {b24.y,b24.y,b24.y,b24.y};
            f32x4 c2v = {b24.z,b24.z,b24.z,b24.z}, c3v = {b24.w,b24.w,b24.w,b24.w};
            c0v = MFMA(ah0, *(const bf16x8*)&sW2T[( 0+cl)*72 +      rg*8], c0v, 0,0,0);
            c0v = MFMA(ah1, *(const bf16x8*)&sW2T[( 0+cl)*72 + 32 + rg*8], c0v, 0,0,0);
            c1v = MFMA(ah0, *(const bf16x8*)&sW2T[(16+cl)*72 +      rg*8], c1v, 0,0,0);
            c1v = MFMA(ah1, *(const bf16x8*)&sW2T[(16+cl)*72 + 32 + rg*8], c1v, 0,0,0);
            c2v = MFMA(ah0, *(const bf16x8*)&sW2T[(32+cl)*72 +      rg*8], c2v, 0,0,0);
            c2v = MFMA(ah1, *(const bf16x8*)&sW2T[(32+cl)*72 + 32 + rg*8], c2v, 0,0,0);
            c3v = MFMA(ah0, *(const bf16x8*)&sW2T[(48+cl)*72 +      rg*8], c3v, 0,0,0);
            c3v = MFMA(ah1, *(const bf16x8*)&sW2T[(48+cl)*72 + 32 + rg*8], c3v, 0,0,0);

            // ---- score (tile t): uniform 24-FMA dot vs sC, xor-reduce over rg ----
            float p_ = 0.f;
            #pragma unroll
            for (int i = 0; i < 8; i++) {
                p_ += bf2f(ax0[i]) * sC[wid][rg*8 + i];
                p_ += bf2f(ax1[i]) * sC[wid][32 + rg*8 + i];
                p_ += bf2f(ax2[i]) * sC[wid][64 + rg*8 + i];
            }
            p_ += __shfl_xor(p_, 16); p_ += __shfl_xor(p_, 32);
            float wgt = (c0 + cl < end) ? __expf(p_ * 0.125f) : 0.f;

            // ---- silu(M1) -> sH1 (tile t), after ah was read ----
            #pragma unroll
            for (int r = 0; r < 4; r++) {
                int row = rg*4 + r;
                float s0 = silu_fast(a0[r]), s1 = silu_fast(a1[r]);
                float s2 = silu_fast(a2[r]), s3 = silu_fast(a3[r]);
                unsigned lo, hi;
                asm("v_cvt_pk_bf16_f32 %0, %1, %2" : "=v"(lo) : "v"(s0), "v"(s1));
                asm("v_cvt_pk_bf16_f32 %0, %1, %2" : "=v"(hi) : "v"(s2), "v"(s3));
                uint2 u; u.x = lo; u.y = hi;
                *(uint2*)&sH1[wid][row*72 + cl*4] = u;
            }

            // ---- accumulate M2 (tile t-1) with w_prev ----
            #pragma unroll
            for (int r = 0; r < 4; r++) {
                float wr = __shfl(w_prev, rg*4 + r);
                hs0 += wr * silu_fast(c0v[r]);
                hs1 += wr * silu_fast(c1v[r]);
                hs2 += wr * silu_fast(c2v[r]);
                hs3 += wr * silu_fast(c3v[r]);
                den += wr;
            }
            w_prev = wgt;
        }

        hs0 += __shfl_xor(hs0, 16); hs0 += __shfl_xor(hs0, 32);
        hs1 += __shfl_xor(hs1, 16); hs1 += __shfl_xor(hs1, 32);
        hs2 += __shfl_xor(hs2, 16); hs2 += __shfl_xor(hs2, 32);
        hs3 += __shfl_xor(hs3, 16); hs3 += __shfl_xor(hs3, 32);
        den += __shfl_xor(den, 16); den += __shfl_xor(den, 32);

        float v = (rg == 0) ? hs0 : (rg == 1) ? hs1 : (rg == 2) ? hs2 : hs3;
        hout[nb + cl*4 + rg] = (den > 0.f) ? v / den : 0.f;
    }
}

// ---------------- node MLP ---------------------------------------------------
__global__ __launch_bounds__(256) void node_out_kernel(
    const float* __restrict__ node_feat,
    const float* __restrict__ W_n1, const float* __restrict__ b_n1,
    const float* __restrict__ W_n2, const float* __restrict__ b_n2,
    const float* __restrict__ hacc, float* __restrict__ out)
{
    __shared__ float sWn1[128*64];
    __shared__ float sWn2[64*64];
    __shared__ __align__(16) float sx[4][64], sg[4][64], st[4][64];

    for (int i = threadIdx.x; i < 128*64; i += 256) sWn1[i] = W_n1[i];
    for (int i = threadIdx.x; i < 64*64; i += 256)  sWn2[i] = W_n2[i];
    __syncthreads();

    const int wid = threadIdx.x >> 6;
    const int lane = threadIdx.x & 63;
    for (int n = blockIdx.x * 4 + wid; n < NN; n += gridDim.x * 4) {
        sx[wid][lane] = node_feat[n*64 + lane];
        sg[wid][lane] = hacc[n*64 + lane];

        float acc = b_n1[lane];
        #pragma unroll
        for (int i = 0; i < 64; i += 4) {
            float4 x4 = *(const float4*)&sx[wid][i];
            float4 g4 = *(const float4*)&sg[wid][i];
            acc += x4.x*sWn1[(i+0)*64+lane] + x4.y*sWn1[(i+1)*64+lane]
                 + x4.z*sWn1[(i+2)*64+lane] + x4.w*sWn1[(i+3)*64+lane];
            acc += g4.x*sWn1[(64+i+0)*64+lane] + g4.y*sWn1[(64+i+1)*64+lane]
                 + g4.z*sWn1[(64+i+2)*64+lane] + g4.w*sWn1[(64+i+3)*64+lane];
        }
        const float tt = silu_f(acc);
        st[wid][lane] = tt;

        float acc2 = b_n2[lane];
        #pragma unroll
        for (int i = 0; i < 64; i += 4) {
            float4 t4 = *(const float4*)&st[wid][i];
            acc2 += t4.x*sWn2[(i+0)*64+lane] + t4.y*sWn2[(i+1)*64+lane]
                  + t4.z*sWn2[(i+2)*64+lane] + t4.w*sWn2[(i+3)*64+lane];
        }
        out[n*64 + lane] = acc2;
    }
}

// ---------------- launch -----------------------------------------------------
extern "C" void kernel_launch(void* const* d_in, const int* in_sizes, int n_in,
                              void* d_out, int out_size, void* d_ws, size_t ws_size,
                              hipStream_t stream) {
    const float* node_feat = (const float*)d_in[0];
    const float* coord     = (const float*)d_in[1];
    const float* edge_feat = (const float*)d_in[2];
    const float* W_e1 = (const float*)d_in[3];
    const float* b_e1 = (const float*)d_in[4];
    const float* W_e2 = (const float*)d_in[5];
    const float* b_e2 = (const float*)d_in[6];
    const float* W_n1 = (const float*)d_in[7];
    const float* b_n1 = (const float*)d_in[8];
    const float* W_n2 = (const float*)d_in[9];
    const float* b_n2 = (const float*)d_in[10];
    const float* W_q  = (const float*)d_in[11];
    const float* W_k  = (const float*)d_in[12];
    const int* src = (const int*)d_in[13];
    const int* dst = (const int*)d_in[14];
    float* out = (float*)d_out;

    float* ws = (float*)d_ws;
    short* nfb       = (short*)ws;                       // NN*64 bf16
    float* B         = ws + 320000;
    float* G         = ws + 960000;
    float* EQn       = ws + 1600000;
    float* WQn       = ws + 1760000;
    int*   cnt       = (int*)(ws + 1770000);
    int*   row_start = (int*)(ws + 1780000);
    int*   cursor    = (int*)(ws + 1790004);
    int*   perm      = (int*)(ws + 1800004);
    int*   src_s     = (int*)(ws + 2440004);
    unsigned short* dist_s = (unsigned short*)(ws + 3080004);
    unsigned short* efs    = (unsigned short*)(ws + 3400004);
    float* hacc      = ws + 8520004;

    hipMemsetAsync(cnt, 0, NN * sizeof(int), stream);

    node_pre_kernel<<<320, 256, 0, stream>>>(node_feat, W_e1, W_k, W_q,
                                             nfb, B, G, EQn, WQn);
    k_hist<<<2500, 256, 0, stream>>>(dst, cnt);
    k_scan<<<1, 256, 0, stream>>>(cnt, row_start, cursor);
    k_scatter<<<2500, 256, 0, stream>>>(dst, cursor, perm);
    k_pack<<<2500, 256, 0, stream>>>(perm, src, dst, edge_feat, coord,
                                     src_s, dist_s, efs);
    edge_kernel<<<625, 512, 0, stream>>>(nfb, src_s, dist_s, efs, row_start,
                                         W_e1, b_e1, W_e2, b_e2,
                                         B, G, EQn, WQn, hacc);
    node_out_kernel<<<320, 256, 0, stream>>>(node_feat, W_n1, b_n1, W_n2, b_n2,
                                             hacc, out);
}

// Round 11
// 358.251 us; speedup vs baseline: 1.7124x; 1.7124x over previous
//
#include <hip/hip_runtime.h>

#define NN 10000
#define NE 640000

typedef __attribute__((ext_vector_type(8))) short bf16x8;
typedef __attribute__((ext_vector_type(4))) short s16x4;
typedef __attribute__((ext_vector_type(4))) float f32x4;

#define MFMA __builtin_amdgcn_mfma_f32_16x16x32_bf16

static __device__ __forceinline__ float silu_f(float x) {
    return x / (1.f + __expf(-x));
}
// fast silu: v_rcp_f32 (1 ulp) — output is bf16-rounded anyway
static __device__ __forceinline__ float silu_fast(float x) {
    float d = 1.f + __expf(-x);
    float r; asm("v_rcp_f32 %0, %1" : "=v"(r) : "v"(d));
    return x * r;
}
static __device__ __forceinline__ short f2bf(float x) {   // RNE f32->bf16
    union { float f; unsigned u; } v; v.f = x;
    unsigned r = (v.u + 0x7FFF + ((v.u >> 16) & 1)) >> 16;
    return (short)r;
}
static __device__ __forceinline__ float bf2f(short h) {
    union { float f; unsigned u; } v; v.u = ((unsigned)(unsigned short)h) << 16;
    return v.f;
}

// ---------------- CSR build ---------------------------------------------------
__global__ __launch_bounds__(256) void k_hist(const int* __restrict__ dst,
                                              int* __restrict__ cnt) {
    int e = blockIdx.x * 256 + threadIdx.x;
    if (e < NE) atomicAdd(&cnt[dst[e]], 1);
}

__global__ __launch_bounds__(256) void k_scan(const int* __restrict__ cnt,
                                              int* __restrict__ row_start,
                                              int* __restrict__ cursor) {
    __shared__ int sv[NN];
    __shared__ int part[256];
    __shared__ int base[257];
    const int t = threadIdx.x;
    for (int i = t; i < NN; i += 256) sv[i] = cnt[i];
    __syncthreads();
    int s = 0;
    #pragma unroll
    for (int i = 0; i < 40; i++) {
        int idx = t * 40 + i;
        int v = (idx < NN) ? sv[idx] : 0;
        if (idx < NN) sv[idx] = s;
        s += v;
    }
    part[t] = s;
    __syncthreads();
    if (t == 0) {
        int a = 0;
        for (int j = 0; j < 256; j++) { base[j] = a; a += part[j]; }
        base[256] = a;
    }
    __syncthreads();
    for (int i = t; i < NN; i += 256) {
        int v = base[i / 40] + sv[i];
        row_start[i] = v; cursor[i] = v;
    }
    if (t == 0) row_start[NN] = base[256];
}

__global__ __launch_bounds__(256) void k_scatter(const int* __restrict__ dst,
                                                 int* __restrict__ cursor,
                                                 int* __restrict__ perm) {
    int e = blockIdx.x * 256 + threadIdx.x;
    if (e < NE) {
        int d = dst[e];
        int p = atomicAdd(&cursor[d], 1);
        perm[p] = e;
    }
}

__global__ __launch_bounds__(256) void k_pack(
    const int* __restrict__ perm, const int* __restrict__ src,
    const int* __restrict__ dst, const float* __restrict__ ef,
    const float* __restrict__ coord,
    int* __restrict__ src_s, unsigned short* __restrict__ dist_s,
    unsigned short* __restrict__ efs)
{
    int p = blockIdx.x * 256 + threadIdx.x;
    if (p >= NE) return;
    const int e = perm[p];
    const int s = src[e];
    const int d = dst[e];

    const float dx = coord[s*3+0] - coord[d*3+0];
    const float dy = coord[s*3+1] - coord[d*3+1];
    const float dz = coord[s*3+2] - coord[d*3+2];
    const float dist = sqrtf(dx*dx + dy*dy + dz*dz);

    src_s[p] = s;
    dist_s[p] = (unsigned short)f2bf(dist);

    const float4* ep = (const float4*)(ef + (size_t)e*16);
    #pragma unroll
    for (int j = 0; j < 4; j++) {
        float4 a = ep[j];
        s16x4 p4;
        p4[0] = f2bf(a.x); p4[1] = f2bf(a.y); p4[2] = f2bf(a.z); p4[3] = f2bf(a.w);
        *(s16x4*)&efs[(size_t)p*16 + j*4] = p4;
    }
}

// ---------------- node precompute --------------------------------------------
__global__ __launch_bounds__(256) void node_pre_kernel(
    const float* __restrict__ node_feat,
    const float* __restrict__ W_e1,   // [145][64]
    const float* __restrict__ W_k,    // [81][64]
    const float* __restrict__ W_q,    // [64][64]
    short* __restrict__ nfb, float* __restrict__ B,
    float* __restrict__ G, float* __restrict__ EQn, float* __restrict__ WQn)
{
    __shared__ float sW1b[64*64];
    __shared__ float sWq[64*64];
    __shared__ float sWk[64*65];
    __shared__ float sWke[16*65];
    __shared__ __align__(16) float sx[4][64];
    __shared__ __align__(16) float sq[4][64];

    for (int i = threadIdx.x; i < 64*64; i += 256) {
        sW1b[i] = W_e1[64*64 + i];
        sWq[i]  = W_q[i];
        int c = i >> 6, j = i & 63;
        sWk[c*65 + j] = W_k[i];
    }
    for (int i = threadIdx.x; i < 16*64; i += 256) {
        int k = i >> 6, j = i & 63;
        sWke[k*65 + j] = W_k[(65 + k)*64 + j];
    }
    __syncthreads();

    const int wid = threadIdx.x >> 6;
    const int lane = threadIdx.x & 63;
    for (int n = blockIdx.x * 4 + wid; n < NN; n += gridDim.x * 4) {
        float x = node_feat[n*64 + lane];
        nfb[n*64 + lane] = f2bf(x);
        sx[wid][lane] = x;
        float b = 0.f, q = 0.f;
        #pragma unroll
        for (int i = 0; i < 64; i += 4) {
            float4 x4 = *(const float4*)&sx[wid][i];
            b += x4.x*sW1b[(i+0)*64+lane] + x4.y*sW1b[(i+1)*64+lane]
               + x4.z*sW1b[(i+2)*64+lane] + x4.w*sW1b[(i+3)*64+lane];
            q += x4.x*sWq[(i+0)*64+lane] + x4.y*sWq[(i+1)*64+lane]
               + x4.z*sWq[(i+2)*64+lane] + x4.w*sWq[(i+3)*64+lane];
        }
        B[n*64 + lane] = b;
        sq[wid][lane] = q;

        float g = 0.f;
        #pragma unroll
        for (int j = 0; j < 64; j += 4) {
            float4 q4 = *(const float4*)&sq[wid][j];
            g += q4.x*sWk[lane*65 + j]   + q4.y*sWk[lane*65 + j+1]
               + q4.z*sWk[lane*65 + j+2] + q4.w*sWk[lane*65 + j+3];
        }
        G[n*64 + lane] = g;

        float p = W_k[64*64 + lane] * q;
        #pragma unroll
        for (int off = 32; off; off >>= 1) p += __shfl_xor(p, off);
        if (lane == 0) WQn[n] = p;

        int kk = lane & 15, pp = lane >> 4;
        float s = 0.f;
        #pragma unroll
        for (int jj = 0; jj < 16; jj++) {
            int j = pp*16 + jj;
            s += sWke[kk*65 + j] * sq[wid][j];
        }
        s += __shfl_xor(s, 16); s += __shfl_xor(s, 32);
        if (lane < 16) EQn[n*16 + kk] = s;
    }
}

// ---------------- edge pass: wave/node, software-pipelined, no sX ------------
// A operands loaded DIRECTLY in MFMA layout: lane(cl,rg) holds edge c0+cl,
// k-chunk rg*8. Score = uniform dot vs sC=[G|EQn|wq|0..] (dist rides k=80).
// Pipeline: M2 of tile t-1 (from sH1) overlaps M1 of tile t; one drain iter.
// NOTE __launch_bounds__(512, 2): on this toolchain (512,4) caps VGPR at 64
// and spills catastrophically (R3, R10 evidence). (512,2) -> cap 128.
__global__ __launch_bounds__(512, 2) void edge_kernel(
    const short* __restrict__ nfb, const int* __restrict__ src_s,
    const unsigned short* __restrict__ dist_s,
    const unsigned short* __restrict__ efs, const int* __restrict__ row_start,
    const float* __restrict__ W_e1, const float* __restrict__ b_e1,
    const float* __restrict__ W_e2, const float* __restrict__ b_e2,
    const float* __restrict__ B, const float* __restrict__ G,
    const float* __restrict__ EQn, const float* __restrict__ WQn,
    float* __restrict__ hout)
{
    __shared__ short sW1T[64*104];     // [phys slot][k], k<96 used, pads zero
    __shared__ short sW2T[64*72];      // [phys slot][k]
    __shared__ short sH1[8][16*72];    // per-wave [edge][logical c]
    __shared__ __align__(16) float sC[8][96];   // per-wave score coeffs

    const int tid = threadIdx.x;
    const int wid = tid >> 6, l = tid & 63;
    const int cl = l & 15, rg = l >> 4;

    for (int i = tid; i < 64*104; i += 512) sW1T[i] = 0;
    __syncthreads();
    for (int i = tid; i < 64*82; i += 512) {
        int k = i >> 6, c = i & 63;              // c = LOGICAL output col
        float v;
        if (k < 64)       v = W_e1[k*64 + c];
        else if (k < 80)  v = W_e1[(129 + k - 64)*64 + c];
        else if (k == 80) v = W_e1[128*64 + c];
        else              v = b_e1[c];
        int s = (c & 3) * 16 + (c >> 2);          // physical MFMA col slot
        sW1T[s*104 + k] = f2bf(v);
    }
    for (int i = tid; i < 64*64; i += 512) {
        int k = i >> 6, c = i & 63;
        int s = (c & 3) * 16 + (c >> 2);
        sW2T[s*72 + k] = f2bf(W_e2[k*64 + c]);
    }
    __syncthreads();

    const float4 b24 = *(const float4*)&b_e2[cl*4];   // same for all nodes

    for (int n = blockIdx.x * 8 + wid; n < NN; n += gridDim.x * 8) {
        const int beg = row_start[n], end = row_start[n+1];
        const size_t nb = (size_t)n*64;
        const float4 Bb4 = *(const float4*)&B[nb + cl*4];

        // score coefficient vector: [0..63]=G, [64..79]=EQn, [80]=wq, [81..95]=0
        sC[wid][l] = G[nb + l];
        if (l < 16) sC[wid][64 + l] = EQn[(size_t)n*16 + l];
        if (l == 16) sC[wid][80] = WQn[n];
        if (l >= 17 && l < 32) sC[wid][64 + l] = 0.f;

        // zero this wave's sH1 (pipeline stage -1)
        {
            unsigned* hp = (unsigned*)&sH1[wid][0];
            #pragma unroll
            for (int i = l; i < 576; i += 64) hp[i] = 0u;
        }

        float hs0 = 0.f, hs1 = 0.f, hs2 = 0.f, hs3 = 0.f, den = 0.f;
        float w_prev = 0.f;

        // ---- prefetch tile 0 (direct, consumer layout) ----
        bf16x8 pA, pB, pE;
        #pragma unroll
        for (int i = 0; i < 8; i++) pE[i] = 0;
        unsigned short pD = 0;
        {
            int idx = beg + cl; if (idx > NE-1) idx = NE-1;
            int sN = src_s[idx];
            pA = *(const bf16x8*)&nfb[(size_t)sN*64 + rg*8];
            pB = *(const bf16x8*)&nfb[(size_t)sN*64 + 32 + rg*8];
            if (rg < 2)       pE = *(const bf16x8*)&efs[(size_t)idx*16 + rg*8];
            else if (rg == 2) pD = dist_s[idx];
        }

        for (int c0 = beg; c0 < end + 16; c0 += 16) {
            // ---- read previous tile's H1 (zeros on first iter) ----
            bf16x8 ah0 = *(const bf16x8*)&sH1[wid][cl*72 + rg*8];
            bf16x8 ah1 = *(const bf16x8*)&sH1[wid][cl*72 + 32 + rg*8];

            // rotate prefetch -> current
            bf16x8 ax0 = pA, ax1 = pB, pEc = pE;
            unsigned short pDc = pD;

            // issue next-tile prefetch
            {
                int idx2 = c0 + 16 + cl; if (idx2 > NE-1) idx2 = NE-1;
                int sN = src_s[idx2];
                pA = *(const bf16x8*)&nfb[(size_t)sN*64 + rg*8];
                pB = *(const bf16x8*)&nfb[(size_t)sN*64 + 32 + rg*8];
                if (rg < 2)       pE = *(const bf16x8*)&efs[(size_t)idx2*16 + rg*8];
                else if (rg == 2) pD = dist_s[idx2];
            }

            // build ax2: rg0/1 = ef chunks, rg2 = {dist, 1, 0..}, rg3 = 0
            bf16x8 ax2;
            #pragma unroll
            for (int i = 0; i < 8; i++) ax2[i] = 0;
            if (rg < 2) ax2 = pEc;
            else if (rg == 2) { ax2[0] = (short)pDc; ax2[1] = (short)0x3F80; }

            // ---- M1 (tile t): K=96, C-init = B[dst] ----
            f32x4 a0 = {Bb4.x,Bb4.x,Bb4.x,Bb4.x}, a1 = {Bb4.y,Bb4.y,Bb4.y,Bb4.y};
            f32x4 a2 = {Bb4.z,Bb4.z,Bb4.z,Bb4.z}, a3 = {Bb4.w,Bb4.w,Bb4.w,Bb4.w};
            a0 = MFMA(ax0, *(const bf16x8*)&sW1T[( 0+cl)*104 +  0 + rg*8], a0, 0,0,0);
            a0 = MFMA(ax1, *(const bf16x8*)&sW1T[( 0+cl)*104 + 32 + rg*8], a0, 0,0,0);
            a0 = MFMA(ax2, *(const bf16x8*)&sW1T[( 0+cl)*104 + 64 + rg*8], a0, 0,0,0);
            a1 = MFMA(ax0, *(const bf16x8*)&sW1T[(16+cl)*104 +  0 + rg*8], a1, 0,0,0);
            a1 = MFMA(ax1, *(const bf16x8*)&sW1T[(16+cl)*104 + 32 + rg*8], a1, 0,0,0);
            a1 = MFMA(ax2, *(const bf16x8*)&sW1T[(16+cl)*104 + 64 + rg*8], a1, 0,0,0);
            a2 = MFMA(ax0, *(const bf16x8*)&sW1T[(32+cl)*104 +  0 + rg*8], a2, 0,0,0);
            a2 = MFMA(ax1, *(const bf16x8*)&sW1T[(32+cl)*104 + 32 + rg*8], a2, 0,0,0);
            a2 = MFMA(ax2, *(const bf16x8*)&sW1T[(32+cl)*104 + 64 + rg*8], a2, 0,0,0);
            a3 = MFMA(ax0, *(const bf16x8*)&sW1T[(48+cl)*104 +  0 + rg*8], a3, 0,0,0);
            a3 = MFMA(ax1, *(const bf16x8*)&sW1T[(48+cl)*104 + 32 + rg*8], a3, 0,0,0);
            a3 = MFMA(ax2, *(const bf16x8*)&sW1T[(48+cl)*104 + 64 + rg*8], a3, 0,0,0);

            // ---- M2 (tile t-1), independent of M1 ----
            f32x4 c0v = {b24.x,b24.x,b24.x,b24.x}, c1v = {b24.y,b24.y,b24.y,b24.y};
            f32x4 c2v = {b24.z,b24.z,b24.z,b24.z}, c3v = {b24.w,b24.w,b24.w,b24.w};
            c0v = MFMA(ah0, *(const bf16x8*)&sW2T[( 0+cl)*72 +      rg*8], c0v, 0,0,0);
            c0v = MFMA(ah1, *(const bf16x8*)&sW2T[( 0+cl)*72 + 32 + rg*8], c0v, 0,0,0);
            c1v = MFMA(ah0, *(const bf16x8*)&sW2T[(16+cl)*72 +      rg*8], c1v, 0,0,0);
            c1v = MFMA(ah1, *(const bf16x8*)&sW2T[(16+cl)*72 + 32 + rg*8], c1v, 0,0,0);
            c2v = MFMA(ah0, *(const bf16x8*)&sW2T[(32+cl)*72 +      rg*8], c2v, 0,0,0);
            c2v = MFMA(ah1, *(const bf16x8*)&sW2T[(32+cl)*72 + 32 + rg*8], c2v, 0,0,0);
            c3v = MFMA(ah0, *(const bf16x8*)&sW2T[(48+cl)*72 +      rg*8], c3v, 0,0,0);
            c3v = MFMA(ah1, *(const bf16x8*)&sW2T[(48+cl)*72 + 32 + rg*8], c3v, 0,0,0);

            // ---- score (tile t): uniform 24-FMA dot vs sC, xor-reduce over rg ----
            float p_ = 0.f;
            #pragma unroll
            for (int i = 0; i < 8; i++) {
                p_ += bf2f(ax0[i]) * sC[wid][rg*8 + i];
                p_ += bf2f(ax1[i]) * sC[wid][32 + rg*8 + i];
                p_ += bf2f(ax2[i]) * sC[wid][64 + rg*8 + i];
            }
            p_ += __shfl_xor(p_, 16); p_ += __shfl_xor(p_, 32);
            float wgt = (c0 + cl < end) ? __expf(p_ * 0.125f) : 0.f;

            // ---- silu(M1) -> sH1 (tile t), after ah was read ----
            #pragma unroll
            for (int r = 0; r < 4; r++) {
                int row = rg*4 + r;
                float s0 = silu_fast(a0[r]), s1 = silu_fast(a1[r]);
                float s2 = silu_fast(a2[r]), s3 = silu_fast(a3[r]);
                unsigned lo, hi;
                asm("v_cvt_pk_bf16_f32 %0, %1, %2" : "=v"(lo) : "v"(s0), "v"(s1));
                asm("v_cvt_pk_bf16_f32 %0, %1, %2" : "=v"(hi) : "v"(s2), "v"(s3));
                uint2 u; u.x = lo; u.y = hi;
                *(uint2*)&sH1[wid][row*72 + cl*4] = u;
            }

            // ---- accumulate M2 (tile t-1) with w_prev ----
            #pragma unroll
            for (int r = 0; r < 4; r++) {
                float wr = __shfl(w_prev, rg*4 + r);
                hs0 += wr * silu_fast(c0v[r]);
                hs1 += wr * silu_fast(c1v[r]);
                hs2 += wr * silu_fast(c2v[r]);
                hs3 += wr * silu_fast(c3v[r]);
                den += wr;
            }
            w_prev = wgt;
        }

        hs0 += __shfl_xor(hs0, 16); hs0 += __shfl_xor(hs0, 32);
        hs1 += __shfl_xor(hs1, 16); hs1 += __shfl_xor(hs1, 32);
        hs2 += __shfl_xor(hs2, 16); hs2 += __shfl_xor(hs2, 32);
        hs3 += __shfl_xor(hs3, 16); hs3 += __shfl_xor(hs3, 32);
        den += __shfl_xor(den, 16); den += __shfl_xor(den, 32);

        float v = (rg == 0) ? hs0 : (rg == 1) ? hs1 : (rg == 2) ? hs2 : hs3;
        hout[nb + cl*4 + rg] = (den > 0.f) ? v / den : 0.f;
    }
}

// ---------------- node MLP ---------------------------------------------------
__global__ __launch_bounds__(256) void node_out_kernel(
    const float* __restrict__ node_feat,
    const float* __restrict__ W_n1, const float* __restrict__ b_n1,
    const float* __restrict__ W_n2, const float* __restrict__ b_n2,
    const float* __restrict__ hacc, float* __restrict__ out)
{
    __shared__ float sWn1[128*64];
    __shared__ float sWn2[64*64];
    __shared__ __align__(16) float sx[4][64], sg[4][64], st[4][64];

    for (int i = threadIdx.x; i < 128*64; i += 256) sWn1[i] = W_n1[i];
    for (int i = threadIdx.x; i < 64*64; i += 256)  sWn2[i] = W_n2[i];
    __syncthreads();

    const int wid = threadIdx.x >> 6;
    const int lane = threadIdx.x & 63;
    for (int n = blockIdx.x * 4 + wid; n < NN; n += gridDim.x * 4) {
        sx[wid][lane] = node_feat[n*64 + lane];
        sg[wid][lane] = hacc[n*64 + lane];

        float acc = b_n1[lane];
        #pragma unroll
        for (int i = 0; i < 64; i += 4) {
            float4 x4 = *(const float4*)&sx[wid][i];
            float4 g4 = *(const float4*)&sg[wid][i];
            acc += x4.x*sWn1[(i+0)*64+lane] + x4.y*sWn1[(i+1)*64+lane]
                 + x4.z*sWn1[(i+2)*64+lane] + x4.w*sWn1[(i+3)*64+lane];
            acc += g4.x*sWn1[(64+i+0)*64+lane] + g4.y*sWn1[(64+i+1)*64+lane]
                 + g4.z*sWn1[(64+i+2)*64+lane] + g4.w*sWn1[(64+i+3)*64+lane];
        }
        const float tt = silu_f(acc);
        st[wid][lane] = tt;

        float acc2 = b_n2[lane];
        #pragma unroll
        for (int i = 0; i < 64; i += 4) {
            float4 t4 = *(const float4*)&st[wid][i];
            acc2 += t4.x*sWn2[(i+0)*64+lane] + t4.y*sWn2[(i+1)*64+lane]
                  + t4.z*sWn2[(i+2)*64+lane] + t4.w*sWn2[(i+3)*64+lane];
        }
        out[n*64 + lane] = acc2;
    }
}

// ---------------- launch -----------------------------------------------------
extern "C" void kernel_launch(void* const* d_in, const int* in_sizes, int n_in,
                              void* d_out, int out_size, void* d_ws, size_t ws_size,
                              hipStream_t stream) {
    const float* node_feat = (const float*)d_in[0];
    const float* coord     = (const float*)d_in[1];
    const float* edge_feat = (const float*)d_in[2];
    const float* W_e1 = (const float*)d_in[3];
    const float* b_e1 = (const float*)d_in[4];
    const float* W_e2 = (const float*)d_in[5];
    const float* b_e2 = (const float*)d_in[6];
    const float* W_n1 = (const float*)d_in[7];
    const float* b_n1 = (const float*)d_in[8];
    const float* W_n2 = (const float*)d_in[9];
    const float* b_n2 = (const float*)d_in[10];
    const float* W_q  = (const float*)d_in[11];
    const float* W_k  = (const float*)d_in[12];
    const int* src = (const int*)d_in[13];
    const int* dst = (const int*)d_in[14];
    float* out = (float*)d_out;

    float* ws = (float*)d_ws;
    short* nfb       = (short*)ws;                       // NN*64 bf16
    float* B         = ws + 320000;
    float* G         = ws + 960000;
    float* EQn       = ws + 1600000;
    float* WQn       = ws + 1760000;
    int*   cnt       = (int*)(ws + 1770000);
    int*   row_start = (int*)(ws + 1780000);
    int*   cursor    = (int*)(ws + 1790004);
    int*   perm      = (int*)(ws + 1800004);
    int*   src_s     = (int*)(ws + 2440004);
    unsigned short* dist_s = (unsigned short*)(ws + 3080004);
    unsigned short* efs    = (unsigned short*)(ws + 3400004);
    float* hacc      = ws + 8520004;

    hipMemsetAsync(cnt, 0, NN * sizeof(int), stream);

    node_pre_kernel<<<320, 256, 0, stream>>>(node_feat, W_e1, W_k, W_q,
                                             nfb, B, G, EQn, WQn);
    k_hist<<<2500, 256, 0, stream>>>(dst, cnt);
    k_scan<<<1, 256, 0, stream>>>(cnt, row_start, cursor);
    k_scatter<<<2500, 256, 0, stream>>>(dst, cursor, perm);
    k_pack<<<2500, 256, 0, stream>>>(perm, src, dst, edge_feat, coord,
                                     src_s, dist_s, efs);
    edge_kernel<<<625, 512, 0, stream>>>(nfb, src_s, dist_s, efs, row_start,
                                         W_e1, b_e1, W_e2, b_e2,
                                         B, G, EQn, WQn, hacc);
    node_out_kernel<<<320, 256, 0, stream>>>(node_feat, W_n1, b_n1, W_n2, b_n2,
                                             hacc, out);
}